// Round 4
// baseline (100.311 us; speedup 1.0000x reference)
//
#include <hip/hip_runtime.h>

#define HH 1024
#define WW 1024
#define NS 16
#define ROWS_PER_BLOCK 8
#define BLOCKS_X (HH / ROWS_PER_BLOCK)   // 128

// ---------------------------------------------------------------------------
// Pass 1: one block per (8 rows, sample). Threshold+bit-pack 8 mask rows
// (1024 bits = 32 u32 each) via shfl merges, and per-row min/max occupied col.
// ---------------------------------------------------------------------------
__global__ __launch_bounds__(256)
void pack_kernel(const float* __restrict__ mask,
                 unsigned int* __restrict__ packed,
                 int* __restrict__ rowMinC,
                 int* __restrict__ rowMaxC) {
    const int s  = blockIdx.y;
    const int r0 = blockIdx.x * ROWS_PER_BLOCK;
    const int t  = threadIdx.x;

    const float4* m4 = (const float4*)(mask + (size_t)s * HH * WW);
    __shared__ int smin[ROWS_PER_BLOCK][4], smax[ROWS_PER_BLOCK][4];

#pragma unroll
    for (int rr = 0; rr < ROWS_PER_BLOCK; ++rr) {
        const int row = r0 + rr;
        float4 v = m4[(size_t)row * 256 + t];          // fully coalesced
        unsigned int w = (v.x >= 0.5f ? 1u : 0u)
                       | (v.y >= 0.5f ? 2u : 0u)
                       | (v.z >= 0.5f ? 4u : 0u)
                       | (v.w >= 0.5f ? 8u : 0u);
        // merge 8 lanes' nibbles -> 32-bit word at lanes t%8==0
        w |= __shfl_down(w, 1) << 4;
        w |= __shfl_down(w, 2) << 8;
        w |= __shfl_down(w, 4) << 16;

        int cmin = WW, cmax = -1;
        if ((t & 7) == 0) {
            int g = t >> 3;                            // word index 0..31
            packed[((size_t)s * HH + row) * 32 + g] = w;
            if (w) {
                cmin = (g << 5) + __builtin_ctz(w);
                cmax = (g << 5) + 31 - __builtin_clz(w);
            }
        }
        for (int off = 32; off > 0; off >>= 1) {
            cmin = min(cmin, __shfl_down(cmin, off));
            cmax = max(cmax, __shfl_down(cmax, off));
        }
        if ((t & 63) == 0) { smin[rr][t >> 6] = cmin; smax[rr][t >> 6] = cmax; }
    }
    __syncthreads();
    if (t < ROWS_PER_BLOCK) {
        int cmin = min(min(smin[t][0], smin[t][1]), min(smin[t][2], smin[t][3]));
        int cmax = max(max(smax[t][0], smax[t][1]), max(smax[t][2], smax[t][3]));
        rowMinC[s * HH + r0 + t] = cmin;
        rowMaxC[s * HH + r0 + t] = cmax;
    }
}

// ---------------------------------------------------------------------------
// Pass 2: one block per (8 rows, sample). Computes bbox inline from row stats
// (L2-broadcast), then identity fast path = flat float4 masked copy using the
// packed bits; general path = scalar bilinear fallback.
// ---------------------------------------------------------------------------
__global__ __launch_bounds__(256)
void resize_kernel(const float* __restrict__ mask,
                   const float* __restrict__ img,
                   const unsigned int* __restrict__ packed,
                   const int* __restrict__ rowMinC,
                   const int* __restrict__ rowMaxC,
                   float* __restrict__ out) {
    const int s  = blockIdx.y;
    const int r0 = blockIdx.x * ROWS_PER_BLOCK;
    const int t  = threadIdx.x;

    // stage this block's 8 rows of packed bits (256 words, 1 word/thread)
    __shared__ unsigned int pw[ROWS_PER_BLOCK][32];
    pw[t >> 5][t & 31] = packed[((size_t)s * HH + r0) * 32 + t];

    // inline bbox reduction over the sample's 1024 row stats
    int minR = HH, maxR = -1, minC = WW, maxC = -1;
#pragma unroll
    for (int m = 0; m < 4; ++m) {
        int r = t + (m << 8);
        int mc = rowMaxC[s * HH + r];
        if (mc >= 0) {
            minR = min(minR, r);
            maxR = max(maxR, r);
            minC = min(minC, rowMinC[s * HH + r]);
            maxC = max(maxC, mc);
        }
    }
    for (int off = 32; off > 0; off >>= 1) {
        minR = min(minR, __shfl_down(minR, off));
        maxR = max(maxR, __shfl_down(maxR, off));
        minC = min(minC, __shfl_down(minC, off));
        maxC = max(maxC, __shfl_down(maxC, off));
    }
    __shared__ int sm[4][4];
    __shared__ int bc[3];                              // c, hstart, wstart
    int wave = t >> 6, lane = t & 63;
    if (lane == 0) { sm[wave][0] = minR; sm[wave][1] = maxR; sm[wave][2] = minC; sm[wave][3] = maxC; }
    __syncthreads();
    if (t == 0) {
        for (int wv = 1; wv < 4; ++wv) {
            minR = min(minR, sm[wv][0]);
            maxR = max(maxR, sm[wv][1]);
            minC = min(minC, sm[wv][2]);
            maxC = max(maxC, sm[wv][3]);
        }
        int xl, xr, yl, yr;
        if (maxR < 0) { xl = 0; xr = HH; } else { xl = max(minR - 1, 0); xr = maxR + 1; }
        if (maxC < 0) { yl = 0; yr = WW; } else { yl = max(minC - 1, 0); yr = maxC + 1; }
        int h = xr - xl, w = yr - yl;
        int c = min(h, w);
        bc[0] = c;
        bc[1] = xl + (h - c) / 2;
        bc[2] = yl + (w - c) / 2;
    }
    __syncthreads();
    const int c = bc[0], hstart = bc[1], wstart = bc[2];

    const float* im = img + (size_t)s * HH * WW * 3;
    float*      ob  = out + (size_t)s * HH * WW * 3;

    if (c == HH && c == WW && hstart == 0 && wstart == 0) {
        // Identity resample: out = bit(pixel) ? img : 0, flat float4 layout.
        const float4* ip = (const float4*)(im + (size_t)r0 * WW * 3);
        float4*       op = (float4*)(ob + (size_t)r0 * WW * 3);
#pragma unroll
        for (int rr = 0; rr < ROWS_PER_BLOCK; ++rr) {
            const unsigned int* pwr = pw[rr];
#pragma unroll
            for (int j = 0; j < 3; ++j) {
                int fi = t + (j << 8);          // float4 index in row, 0..767
                int F  = fi << 2;               // float offset in row
                int p0 = F / 3;                 // first pixel covered
                int r  = F - p0 * 3;            // 0..2
                unsigned int b0 = (pwr[p0 >> 5] >> (p0 & 31)) & 1u;
                int p1 = p0 + 1;
                unsigned int b1 = (pwr[p1 >> 5] >> (p1 & 31)) & 1u;
                size_t off = (size_t)rr * 768 + fi;
                float4 v = ip[off];
                float4 o;
                o.x = b0 ? v.x : 0.0f;
                o.y = ((r < 2) ? b0 : b1) ? v.y : 0.0f;
                o.z = ((r == 0) ? b0 : b1) ? v.z : 0.0f;
                o.w = b1 ? v.w : 0.0f;
                op[off] = o;
            }
        }
        return;
    }

    // General path: scalar bilinear gather per pixel.
    const float* msk = mask + (size_t)s * HH * WW;
    float cf = (float)c;
    float sy = cf / (float)HH;
    float sx = cf / (float)WW;

    for (int rr = 0; rr < ROWS_PER_BLOCK; ++rr) {
        const int row = r0 + rr;
        float ysf = fminf(fmaxf((row + 0.5f) * sy - 0.5f, 0.0f), cf - 1.0f);
        int   y0i = (int)floorf(ysf);
        float wy  = ysf - (float)y0i;
        int   ry0 = hstart + y0i;
        int   ry1 = min(ry0 + 1, hstart + c - 1);
        float* orow = ob + (size_t)row * WW * 3;

        for (int k = 0; k < 4; ++k) {
            int ox = (t << 2) + k;
            float xsf = fminf(fmaxf((ox + 0.5f) * sx - 0.5f, 0.0f), cf - 1.0f);
            int   x0i = (int)floorf(xsf);
            float wx  = xsf - (float)x0i;
            int   rx0 = wstart + x0i;
            int   rx1 = min(rx0 + 1, wstart + c - 1);

            float p00[3], p01[3], p10[3], p11[3];
            auto fetch = [&](int y, int x, float* p) {
                int idx = y * WW + x;
                float mv = msk[idx];
                if (mv >= 0.5f) {
                    const float* q = im + (size_t)idx * 3;
                    p[0] = q[0]; p[1] = q[1]; p[2] = q[2];
                } else {
                    p[0] = 0.0f; p[1] = 0.0f; p[2] = 0.0f;
                }
            };
            fetch(ry0, rx0, p00);
            fetch(ry0, rx1, p01);
            fetch(ry1, rx0, p10);
            fetch(ry1, rx1, p11);

            float* o = orow + (size_t)ox * 3;
#pragma unroll
            for (int ch = 0; ch < 3; ++ch) {
                float top = (1.0f - wx) * p00[ch] + wx * p01[ch];
                float bot = (1.0f - wx) * p10[ch] + wx * p11[ch];
                o[ch] = (1.0f - wy) * top + wy * bot;
            }
        }
    }
}

extern "C" void kernel_launch(void* const* d_in, const int* in_sizes, int n_in,
                              void* d_out, int out_size, void* d_ws, size_t ws_size,
                              hipStream_t stream) {
    const float* masks  = (const float*)d_in[0];
    const float* images = (const float*)d_in[1];
    float* out = (float*)d_out;

    // workspace layout
    int* rowMinC     = (int*)d_ws;                            // NS*HH ints
    int* rowMaxC     = rowMinC + NS * HH;                     // NS*HH ints
    unsigned int* pk = (unsigned int*)(rowMaxC + NS * HH);    // NS*HH*32 u32

    pack_kernel  <<<dim3(BLOCKS_X, NS), 256, 0, stream>>>(masks, pk, rowMinC, rowMaxC);
    resize_kernel<<<dim3(BLOCKS_X, NS), 256, 0, stream>>>(masks, images, pk, rowMinC, rowMaxC, out);
}

// Round 5
// 93.032 us; speedup vs baseline: 1.0782x; 1.0782x over previous
//
#include <hip/hip_runtime.h>

#define HH 1024
#define WW 1024
#define NS 16
#define PR 4                    // rows per pack block
#define RB 4                    // rows per resize block

typedef float f32x4 __attribute__((ext_vector_type(4)));

// ---------------------------------------------------------------------------
// Pass 1: one block per (4 rows, sample). Threshold+bit-pack mask rows via
// shfl merges (1024 bits = 32 u32 per row), per-row min/max occupied column.
// Mask is read once -> nontemporal loads.
// ---------------------------------------------------------------------------
__global__ __launch_bounds__(256)
void pack_kernel(const float* __restrict__ mask,
                 unsigned int* __restrict__ packed,
                 int* __restrict__ rowMinC,
                 int* __restrict__ rowMaxC) {
    const int s  = blockIdx.y;
    const int r0 = blockIdx.x * PR;
    const int t  = threadIdx.x;

    const f32x4* m4 = (const f32x4*)(mask + (size_t)s * HH * WW);
    __shared__ int smin[PR][4], smax[PR][4];

    for (int rr = 0; rr < PR; ++rr) {
        const int row = r0 + rr;
        f32x4 v = __builtin_nontemporal_load(&m4[(size_t)row * 256 + t]);
        unsigned int w = (v.x >= 0.5f ? 1u : 0u)
                       | (v.y >= 0.5f ? 2u : 0u)
                       | (v.z >= 0.5f ? 4u : 0u)
                       | (v.w >= 0.5f ? 8u : 0u);
        // merge 8 lanes' nibbles -> full u32 at lanes t%8==0
        w |= __shfl_down(w, 1) << 4;
        w |= __shfl_down(w, 2) << 8;
        w |= __shfl_down(w, 4) << 16;

        int cmin = WW, cmax = -1;
        if ((t & 7) == 0) {
            int g = t >> 3;                            // word index 0..31
            packed[((size_t)s * HH + row) * 32 + g] = w;   // cached: re-read soon
            if (w) {
                cmin = (g << 5) + __builtin_ctz(w);
                cmax = (g << 5) + 31 - __builtin_clz(w);
            }
        }
        for (int off = 32; off > 0; off >>= 1) {
            cmin = min(cmin, __shfl_down(cmin, off));
            cmax = max(cmax, __shfl_down(cmax, off));
        }
        if ((t & 63) == 0) { smin[rr][t >> 6] = cmin; smax[rr][t >> 6] = cmax; }
    }
    __syncthreads();
    if (t < PR) {
        int cmin = min(min(smin[t][0], smin[t][1]), min(smin[t][2], smin[t][3]));
        int cmax = max(max(smax[t][0], smax[t][1]), max(smax[t][2], smax[t][3]));
        rowMinC[s * HH + r0 + t] = cmin;
        rowMaxC[s * HH + r0 + t] = cmax;
    }
}

// ---------------------------------------------------------------------------
// Pass 2: one block per sample reduces 1024 row stats -> (c, hstart, wstart).
// Resize then needs only 3 scalar loads - no per-block reduction.
// ---------------------------------------------------------------------------
__global__ __launch_bounds__(256)
void reduce_kernel(const int* __restrict__ rowMinC,
                   const int* __restrict__ rowMaxC,
                   int* __restrict__ bc4) {
    const int s = blockIdx.x;
    const int t = threadIdx.x;
    int minR = HH, maxR = -1, minC = WW, maxC = -1;
#pragma unroll
    for (int m = 0; m < HH / 256; ++m) {
        int r = t + (m << 8);
        int mc = rowMaxC[s * HH + r];
        if (mc >= 0) {
            minR = min(minR, r);
            maxR = max(maxR, r);
            minC = min(minC, rowMinC[s * HH + r]);
            maxC = max(maxC, mc);
        }
    }
    for (int off = 32; off > 0; off >>= 1) {
        minR = min(minR, __shfl_down(minR, off));
        maxR = max(maxR, __shfl_down(maxR, off));
        minC = min(minC, __shfl_down(minC, off));
        maxC = max(maxC, __shfl_down(maxC, off));
    }
    __shared__ int sm[4][4];
    int wave = t >> 6, lane = t & 63;
    if (lane == 0) { sm[wave][0] = minR; sm[wave][1] = maxR; sm[wave][2] = minC; sm[wave][3] = maxC; }
    __syncthreads();
    if (t == 0) {
        for (int wv = 1; wv < 4; ++wv) {
            minR = min(minR, sm[wv][0]);
            maxR = max(maxR, sm[wv][1]);
            minC = min(minC, sm[wv][2]);
            maxC = max(maxC, sm[wv][3]);
        }
        int xl, xr, yl, yr;
        if (maxR < 0) { xl = 0; xr = HH; } else { xl = max(minR - 1, 0); xr = maxR + 1; }
        if (maxC < 0) { yl = 0; yr = WW; } else { yl = max(minC - 1, 0); yr = maxC + 1; }
        int h = xr - xl, w = yr - yl;
        int c = min(h, w);
        bc4[s * 4 + 0] = c;
        bc4[s * 4 + 1] = xl + (h - c) / 2;
        bc4[s * 4 + 2] = yl + (w - c) / 2;
        bc4[s * 4 + 3] = 0;
    }
}

// ---------------------------------------------------------------------------
// Pass 3: one block per (4 rows, sample). Minimal prologue (3 scalar loads +
// 128-word LDS stage). Identity fast path: flat f32x4 masked copy with
// nontemporal load/store. General path: scalar bilinear fallback.
// ---------------------------------------------------------------------------
__global__ __launch_bounds__(256)
void resize_kernel(const float* __restrict__ mask,
                   const float* __restrict__ img,
                   const unsigned int* __restrict__ packed,
                   const int* __restrict__ bc4,
                   float* __restrict__ out) {
    const int s  = blockIdx.y;
    const int r0 = blockIdx.x * RB;
    const int t  = threadIdx.x;

    __shared__ unsigned int pw[RB][32];
    if (t < RB * 32) pw[t >> 5][t & 31] = packed[((size_t)s * HH + r0) * 32 + t];

    const int c      = bc4[s * 4 + 0];
    const int hstart = bc4[s * 4 + 1];
    const int wstart = bc4[s * 4 + 2];
    __syncthreads();

    const float* im = img + (size_t)s * HH * WW * 3;
    float*       ob = out + (size_t)s * HH * WW * 3;

    if (c == HH && c == WW && hstart == 0 && wstart == 0) {
        // Identity resample: out = bit(pixel) ? img : 0, flat f32x4 layout.
        const f32x4* ip = (const f32x4*)(im + (size_t)r0 * WW * 3);
        f32x4*       op = (f32x4*)(ob + (size_t)r0 * WW * 3);
        for (int rr = 0; rr < RB; ++rr) {
            const unsigned int* pwr = pw[rr];
#pragma unroll
            for (int j = 0; j < 3; ++j) {
                int fi = t + (j << 8);          // f32x4 index in row, 0..767
                int F  = fi << 2;               // float offset in row
                int p0 = F / 3;                 // first pixel covered
                int r  = F - p0 * 3;            // 0..2
                unsigned int b0 = (pwr[p0 >> 5] >> (p0 & 31)) & 1u;
                int p1 = p0 + 1;
                unsigned int b1 = (pwr[p1 >> 5] >> (p1 & 31)) & 1u;
                size_t off = (size_t)rr * 768 + fi;
                f32x4 v = __builtin_nontemporal_load(&ip[off]);
                f32x4 o;
                o.x = b0 ? v.x : 0.0f;
                o.y = ((r < 2) ? b0 : b1) ? v.y : 0.0f;
                o.z = ((r == 0) ? b0 : b1) ? v.z : 0.0f;
                o.w = b1 ? v.w : 0.0f;
                __builtin_nontemporal_store(o, &op[off]);
            }
        }
        return;
    }

    // General path: scalar bilinear gather per pixel.
    const float* msk = mask + (size_t)s * HH * WW;
    float cf = (float)c;
    float sy = cf / (float)HH;
    float sx = cf / (float)WW;

    for (int rr = 0; rr < RB; ++rr) {
        const int row = r0 + rr;
        float ysf = fminf(fmaxf((row + 0.5f) * sy - 0.5f, 0.0f), cf - 1.0f);
        int   y0i = (int)floorf(ysf);
        float wy  = ysf - (float)y0i;
        int   ry0 = hstart + y0i;
        int   ry1 = min(ry0 + 1, hstart + c - 1);
        float* orow = ob + (size_t)row * WW * 3;

        for (int k = 0; k < 4; ++k) {
            int ox = (t << 2) + k;
            float xsf = fminf(fmaxf((ox + 0.5f) * sx - 0.5f, 0.0f), cf - 1.0f);
            int   x0i = (int)floorf(xsf);
            float wx  = xsf - (float)x0i;
            int   rx0 = wstart + x0i;
            int   rx1 = min(rx0 + 1, wstart + c - 1);

            float p00[3], p01[3], p10[3], p11[3];
            auto fetch = [&](int y, int x, float* p) {
                int idx = y * WW + x;
                float mv = msk[idx];
                if (mv >= 0.5f) {
                    const float* q = im + (size_t)idx * 3;
                    p[0] = q[0]; p[1] = q[1]; p[2] = q[2];
                } else {
                    p[0] = 0.0f; p[1] = 0.0f; p[2] = 0.0f;
                }
            };
            fetch(ry0, rx0, p00);
            fetch(ry0, rx1, p01);
            fetch(ry1, rx0, p10);
            fetch(ry1, rx1, p11);

            float* o = orow + (size_t)ox * 3;
#pragma unroll
            for (int ch = 0; ch < 3; ++ch) {
                float top = (1.0f - wx) * p00[ch] + wx * p01[ch];
                float bot = (1.0f - wx) * p10[ch] + wx * p11[ch];
                o[ch] = (1.0f - wy) * top + wy * bot;
            }
        }
    }
}

extern "C" void kernel_launch(void* const* d_in, const int* in_sizes, int n_in,
                              void* d_out, int out_size, void* d_ws, size_t ws_size,
                              hipStream_t stream) {
    const float* masks  = (const float*)d_in[0];
    const float* images = (const float*)d_in[1];
    float* out = (float*)d_out;

    // workspace layout
    int* rowMinC     = (int*)d_ws;                            // NS*HH ints
    int* rowMaxC     = rowMinC + NS * HH;                     // NS*HH ints
    int* bc4         = rowMaxC + NS * HH;                     // NS*4 ints
    unsigned int* pk = (unsigned int*)(bc4 + NS * 4);         // NS*HH*32 u32

    pack_kernel  <<<dim3(HH / PR, NS), 256, 0, stream>>>(masks, pk, rowMinC, rowMaxC);
    reduce_kernel<<<NS,                256, 0, stream>>>(rowMinC, rowMaxC, bc4);
    resize_kernel<<<dim3(HH / RB, NS), 256, 0, stream>>>(masks, images, pk, bc4, out);
}

// Round 6
// 88.875 us; speedup vs baseline: 1.1287x; 1.0468x over previous
//
#include <hip/hip_runtime.h>

#define HH 1024
#define WW 1024
#define NS 16
#define RB 4                    // rows per block (fused + fixup)

typedef float f32x4 __attribute__((ext_vector_type(4)));

// ---------------------------------------------------------------------------
// Pass 1 (fused): one block per (4 rows, sample).
//  - threshold mask rows -> bits (LDS) + per-row min/max col (global stats)
//  - speculatively write the IDENTITY-crop result: out = bit ? img : 0
// If the crop turns out non-identity, pass 3 rewrites the output.
// Carries all irreducible HBM traffic (mask+img read, out write) in one pass.
// ---------------------------------------------------------------------------
__global__ __launch_bounds__(256)
void fused_kernel(const float* __restrict__ mask,
                  const float* __restrict__ img,
                  int* __restrict__ rowMinC,
                  int* __restrict__ rowMaxC,
                  float* __restrict__ out) {
    const int s  = blockIdx.y;
    const int r0 = blockIdx.x * RB;
    const int t  = threadIdx.x;

    const f32x4* m4 = (const f32x4*)(mask + (size_t)s * HH * WW);
    __shared__ unsigned int pw[RB][32];
    __shared__ int smin[RB][4], smax[RB][4];

    for (int rr = 0; rr < RB; ++rr) {
        const int row = r0 + rr;
        f32x4 v = __builtin_nontemporal_load(&m4[(size_t)row * 256 + t]);
        unsigned int w = (v.x >= 0.5f ? 1u : 0u)
                       | (v.y >= 0.5f ? 2u : 0u)
                       | (v.z >= 0.5f ? 4u : 0u)
                       | (v.w >= 0.5f ? 8u : 0u);
        // merge 8 lanes' nibbles -> full u32 at lanes t%8==0
        w |= __shfl_down(w, 1) << 4;
        w |= __shfl_down(w, 2) << 8;
        w |= __shfl_down(w, 4) << 16;

        int cmin = WW, cmax = -1;
        if ((t & 7) == 0) {
            int g = t >> 3;                            // word index 0..31
            pw[rr][g] = w;
            if (w) {
                cmin = (g << 5) + __builtin_ctz(w);
                cmax = (g << 5) + 31 - __builtin_clz(w);
            }
        }
        for (int off = 32; off > 0; off >>= 1) {
            cmin = min(cmin, __shfl_down(cmin, off));
            cmax = max(cmax, __shfl_down(cmax, off));
        }
        if ((t & 63) == 0) { smin[rr][t >> 6] = cmin; smax[rr][t >> 6] = cmax; }
    }
    __syncthreads();
    if (t < RB) {
        int cmin = min(min(smin[t][0], smin[t][1]), min(smin[t][2], smin[t][3]));
        int cmax = max(max(smax[t][0], smax[t][1]), max(smax[t][2], smax[t][3]));
        rowMinC[s * HH + r0 + t] = cmin;
        rowMaxC[s * HH + r0 + t] = cmax;
    }

    // Speculative identity output: flat f32x4 masked copy of img.
    const f32x4* ip = (const f32x4*)(img + ((size_t)s * HH + r0) * WW * 3);
    f32x4*       op = (f32x4*)(out + ((size_t)s * HH + r0) * WW * 3);
    for (int rr = 0; rr < RB; ++rr) {
        const unsigned int* pwr = pw[rr];
#pragma unroll
        for (int j = 0; j < 3; ++j) {
            int fi = t + (j << 8);          // f32x4 index in row, 0..767
            int F  = fi << 2;               // float offset in row
            int p0 = F / 3;                 // first pixel covered
            int r  = F - p0 * 3;            // 0..2
            unsigned int b0 = (pwr[p0 >> 5] >> (p0 & 31)) & 1u;
            int p1 = p0 + 1;
            unsigned int b1 = (pwr[p1 >> 5] >> (p1 & 31)) & 1u;
            size_t off = (size_t)rr * 768 + fi;
            f32x4 v = __builtin_nontemporal_load(&ip[off]);
            f32x4 o;
            o.x = b0 ? v.x : 0.0f;
            o.y = ((r < 2) ? b0 : b1) ? v.y : 0.0f;
            o.z = ((r == 0) ? b0 : b1) ? v.z : 0.0f;
            o.w = b1 ? v.w : 0.0f;
            __builtin_nontemporal_store(o, &op[off]);
        }
    }
}

// ---------------------------------------------------------------------------
// Pass 2: one block per sample reduces 1024 row stats -> (c, hstart, wstart).
// ---------------------------------------------------------------------------
__global__ __launch_bounds__(256)
void reduce_kernel(const int* __restrict__ rowMinC,
                   const int* __restrict__ rowMaxC,
                   int* __restrict__ bc4) {
    const int s = blockIdx.x;
    const int t = threadIdx.x;
    int minR = HH, maxR = -1, minC = WW, maxC = -1;
#pragma unroll
    for (int m = 0; m < HH / 256; ++m) {
        int r = t + (m << 8);
        int mc = rowMaxC[s * HH + r];
        if (mc >= 0) {
            minR = min(minR, r);
            maxR = max(maxR, r);
            minC = min(minC, rowMinC[s * HH + r]);
            maxC = max(maxC, mc);
        }
    }
    for (int off = 32; off > 0; off >>= 1) {
        minR = min(minR, __shfl_down(minR, off));
        maxR = max(maxR, __shfl_down(maxR, off));
        minC = min(minC, __shfl_down(minC, off));
        maxC = max(maxC, __shfl_down(maxC, off));
    }
    __shared__ int sm[4][4];
    int wave = t >> 6, lane = t & 63;
    if (lane == 0) { sm[wave][0] = minR; sm[wave][1] = maxR; sm[wave][2] = minC; sm[wave][3] = maxC; }
    __syncthreads();
    if (t == 0) {
        for (int wv = 1; wv < 4; ++wv) {
            minR = min(minR, sm[wv][0]);
            maxR = max(maxR, sm[wv][1]);
            minC = min(minC, sm[wv][2]);
            maxC = max(maxC, sm[wv][3]);
        }
        int xl, xr, yl, yr;
        if (maxR < 0) { xl = 0; xr = HH; } else { xl = max(minR - 1, 0); xr = maxR + 1; }
        if (maxC < 0) { yl = 0; yr = WW; } else { yl = max(minC - 1, 0); yr = maxC + 1; }
        int h = xr - xl, w = yr - yl;
        int c = min(h, w);
        bc4[s * 4 + 0] = c;
        bc4[s * 4 + 1] = xl + (h - c) / 2;
        bc4[s * 4 + 2] = yl + (w - c) / 2;
        bc4[s * 4 + 3] = 0;
    }
}

// ---------------------------------------------------------------------------
// Pass 3 (fixup): if the crop is the identity, the speculative output is
// already exact -> return. Otherwise rewrite with the general bilinear path.
// ---------------------------------------------------------------------------
__global__ __launch_bounds__(256)
void fixup_kernel(const float* __restrict__ mask,
                  const float* __restrict__ img,
                  const int* __restrict__ bc4,
                  float* __restrict__ out) {
    const int s  = blockIdx.y;
    const int c      = bc4[s * 4 + 0];
    const int hstart = bc4[s * 4 + 1];
    const int wstart = bc4[s * 4 + 2];
    if (c == HH && hstart == 0 && wstart == 0) return;   // speculation was exact

    const int r0 = blockIdx.x * RB;
    const int t  = threadIdx.x;
    const float* msk = mask + (size_t)s * HH * WW;
    const float* im  = img  + (size_t)s * HH * WW * 3;
    float*       ob  = out  + (size_t)s * HH * WW * 3;

    float cf = (float)c;
    float sy = cf / (float)HH;
    float sx = cf / (float)WW;

    for (int rr = 0; rr < RB; ++rr) {
        const int row = r0 + rr;
        float ysf = fminf(fmaxf((row + 0.5f) * sy - 0.5f, 0.0f), cf - 1.0f);
        int   y0i = (int)floorf(ysf);
        float wy  = ysf - (float)y0i;
        int   ry0 = hstart + y0i;
        int   ry1 = min(ry0 + 1, hstart + c - 1);
        float* orow = ob + (size_t)row * WW * 3;

        for (int k = 0; k < 4; ++k) {
            int ox = (t << 2) + k;
            float xsf = fminf(fmaxf((ox + 0.5f) * sx - 0.5f, 0.0f), cf - 1.0f);
            int   x0i = (int)floorf(xsf);
            float wx  = xsf - (float)x0i;
            int   rx0 = wstart + x0i;
            int   rx1 = min(rx0 + 1, wstart + c - 1);

            float p00[3], p01[3], p10[3], p11[3];
            auto fetch = [&](int y, int x, float* p) {
                int idx = y * WW + x;
                float mv = msk[idx];
                if (mv >= 0.5f) {
                    const float* q = im + (size_t)idx * 3;
                    p[0] = q[0]; p[1] = q[1]; p[2] = q[2];
                } else {
                    p[0] = 0.0f; p[1] = 0.0f; p[2] = 0.0f;
                }
            };
            fetch(ry0, rx0, p00);
            fetch(ry0, rx1, p01);
            fetch(ry1, rx0, p10);
            fetch(ry1, rx1, p11);

            float* o = orow + (size_t)ox * 3;
#pragma unroll
            for (int ch = 0; ch < 3; ++ch) {
                float top = (1.0f - wx) * p00[ch] + wx * p01[ch];
                float bot = (1.0f - wx) * p10[ch] + wx * p11[ch];
                o[ch] = (1.0f - wy) * top + wy * bot;
            }
        }
    }
}

extern "C" void kernel_launch(void* const* d_in, const int* in_sizes, int n_in,
                              void* d_out, int out_size, void* d_ws, size_t ws_size,
                              hipStream_t stream) {
    const float* masks  = (const float*)d_in[0];
    const float* images = (const float*)d_in[1];
    float* out = (float*)d_out;

    // workspace layout
    int* rowMinC = (int*)d_ws;                 // NS*HH ints
    int* rowMaxC = rowMinC + NS * HH;          // NS*HH ints
    int* bc4     = rowMaxC + NS * HH;          // NS*4 ints

    fused_kernel <<<dim3(HH / RB, NS), 256, 0, stream>>>(masks, images, rowMinC, rowMaxC, out);
    reduce_kernel<<<NS,                256, 0, stream>>>(rowMinC, rowMaxC, bc4);
    fixup_kernel <<<dim3(HH / RB, NS), 256, 0, stream>>>(masks, images, bc4, out);
}

// Round 7
// 84.936 us; speedup vs baseline: 1.1810x; 1.0464x over previous
//
#include <hip/hip_runtime.h>

#define HH 1024
#define WW 1024
#define NS 16
#define RB 4                    // rows per fused block

typedef float f32x4 __attribute__((ext_vector_type(4)));

// ---------------------------------------------------------------------------
// Pass 1 (fused): one block per (4 rows, sample).
//  - preload 4 mask f32x4 + 12 img f32x4 per thread (16 loads in flight)
//  - threshold+bit-pack mask rows (shfl merges) -> LDS bits + row stats
//  - speculatively write the IDENTITY-crop result: out = bit ? img : 0
// Non-identity crops are rewritten by the tail kernel.
// ---------------------------------------------------------------------------
__global__ __launch_bounds__(256)
void fused_kernel(const float* __restrict__ mask,
                  const float* __restrict__ img,
                  int* __restrict__ rowMinC,
                  int* __restrict__ rowMaxC,
                  float* __restrict__ out) {
    const int s  = blockIdx.y;
    const int r0 = blockIdx.x * RB;
    const int t  = threadIdx.x;

    const f32x4* m4 = (const f32x4*)(mask + (size_t)s * HH * WW);
    const f32x4* ip = (const f32x4*)(img + ((size_t)s * HH + r0) * WW * 3);
    f32x4*       op = (f32x4*)(out + ((size_t)s * HH + r0) * WW * 3);

    // ---- issue ALL loads first (maximum memory-level parallelism) ----
    f32x4 mv[RB];
#pragma unroll
    for (int rr = 0; rr < RB; ++rr)
        mv[rr] = __builtin_nontemporal_load(&m4[(size_t)(r0 + rr) * 256 + t]);

    f32x4 iv[RB][3];
#pragma unroll
    for (int rr = 0; rr < RB; ++rr)
#pragma unroll
        for (int j = 0; j < 3; ++j)
            iv[rr][j] = __builtin_nontemporal_load(&ip[(size_t)rr * 768 + t + (j << 8)]);

    // ---- mask phase: pack bits, per-row min/max col (runs under load latency) ----
    __shared__ unsigned int pw[RB][32];
    __shared__ int smin[RB][4], smax[RB][4];

#pragma unroll
    for (int rr = 0; rr < RB; ++rr) {
        unsigned int w = (mv[rr].x >= 0.5f ? 1u : 0u)
                       | (mv[rr].y >= 0.5f ? 2u : 0u)
                       | (mv[rr].z >= 0.5f ? 4u : 0u)
                       | (mv[rr].w >= 0.5f ? 8u : 0u);
        w |= __shfl_down(w, 1) << 4;
        w |= __shfl_down(w, 2) << 8;
        w |= __shfl_down(w, 4) << 16;

        int cmin = WW, cmax = -1;
        if ((t & 7) == 0) {
            int g = t >> 3;                            // word index 0..31
            pw[rr][g] = w;
            if (w) {
                cmin = (g << 5) + __builtin_ctz(w);
                cmax = (g << 5) + 31 - __builtin_clz(w);
            }
        }
        for (int off = 32; off > 0; off >>= 1) {
            cmin = min(cmin, __shfl_down(cmin, off));
            cmax = max(cmax, __shfl_down(cmax, off));
        }
        if ((t & 63) == 0) { smin[rr][t >> 6] = cmin; smax[rr][t >> 6] = cmax; }
    }
    __syncthreads();
    if (t < RB) {
        int cmin = min(min(smin[t][0], smin[t][1]), min(smin[t][2], smin[t][3]));
        int cmax = max(max(smax[t][0], smax[t][1]), max(smax[t][2], smax[t][3]));
        rowMinC[s * HH + r0 + t] = cmin;
        rowMaxC[s * HH + r0 + t] = cmax;
    }

    // ---- select + store (img already in registers) ----
#pragma unroll
    for (int rr = 0; rr < RB; ++rr) {
        const unsigned int* pwr = pw[rr];
#pragma unroll
        for (int j = 0; j < 3; ++j) {
            int fi = t + (j << 8);          // f32x4 index in row, 0..767
            int F  = fi << 2;               // float offset in row
            int p0 = F / 3;                 // first pixel covered
            int r  = F - p0 * 3;            // 0..2
            unsigned int b0 = (pwr[p0 >> 5] >> (p0 & 31)) & 1u;
            int p1 = p0 + 1;
            unsigned int b1 = (pwr[p1 >> 5] >> (p1 & 31)) & 1u;
            f32x4 v = iv[rr][j];
            f32x4 o;
            o.x = b0 ? v.x : 0.0f;
            o.y = ((r < 2) ? b0 : b1) ? v.y : 0.0f;
            o.z = ((r == 0) ? b0 : b1) ? v.z : 0.0f;
            o.w = b1 ? v.w : 0.0f;
            __builtin_nontemporal_store(o, &op[(size_t)rr * 768 + fi]);
        }
    }
}

// ---------------------------------------------------------------------------
// Pass 2 (tail): one block per sample. Reduce row stats -> crop params.
// Identity crop (the speculated case) -> return. Otherwise rewrite the whole
// sample with the general bilinear path (correctness fallback).
// ---------------------------------------------------------------------------
__global__ __launch_bounds__(256)
void tail_kernel(const float* __restrict__ mask,
                 const float* __restrict__ img,
                 const int* __restrict__ rowMinC,
                 const int* __restrict__ rowMaxC,
                 float* __restrict__ out) {
    const int s = blockIdx.x;
    const int t = threadIdx.x;

    int minR = HH, maxR = -1, minC = WW, maxC = -1;
#pragma unroll
    for (int m = 0; m < HH / 256; ++m) {
        int r = t + (m << 8);
        int mc = rowMaxC[s * HH + r];
        if (mc >= 0) {
            minR = min(minR, r);
            maxR = max(maxR, r);
            minC = min(minC, rowMinC[s * HH + r]);
            maxC = max(maxC, mc);
        }
    }
    for (int off = 32; off > 0; off >>= 1) {
        minR = min(minR, __shfl_down(minR, off));
        maxR = max(maxR, __shfl_down(maxR, off));
        minC = min(minC, __shfl_down(minC, off));
        maxC = max(maxC, __shfl_down(maxC, off));
    }
    __shared__ int sm[4][4];
    __shared__ int bc[3];
    int wave = t >> 6, lane = t & 63;
    if (lane == 0) { sm[wave][0] = minR; sm[wave][1] = maxR; sm[wave][2] = minC; sm[wave][3] = maxC; }
    __syncthreads();
    if (t == 0) {
        for (int wv = 1; wv < 4; ++wv) {
            minR = min(minR, sm[wv][0]);
            maxR = max(maxR, sm[wv][1]);
            minC = min(minC, sm[wv][2]);
            maxC = max(maxC, sm[wv][3]);
        }
        int xl, xr, yl, yr;
        if (maxR < 0) { xl = 0; xr = HH; } else { xl = max(minR - 1, 0); xr = maxR + 1; }
        if (maxC < 0) { yl = 0; yr = WW; } else { yl = max(minC - 1, 0); yr = maxC + 1; }
        int h = xr - xl, w = yr - yl;
        int c = min(h, w);
        bc[0] = c;
        bc[1] = xl + (h - c) / 2;
        bc[2] = yl + (w - c) / 2;
    }
    __syncthreads();
    const int c = bc[0], hstart = bc[1], wstart = bc[2];
    if (c == HH && hstart == 0 && wstart == 0) return;   // speculation was exact

    // General bilinear rewrite of the whole sample (rare fallback path).
    const float* msk = mask + (size_t)s * HH * WW;
    const float* im  = img  + (size_t)s * HH * WW * 3;
    float*       ob  = out  + (size_t)s * HH * WW * 3;

    float cf = (float)c;
    float sy = cf / (float)HH;
    float sx = cf / (float)WW;

    for (int row = 0; row < HH; ++row) {
        float ysf = fminf(fmaxf((row + 0.5f) * sy - 0.5f, 0.0f), cf - 1.0f);
        int   y0i = (int)floorf(ysf);
        float wy  = ysf - (float)y0i;
        int   ry0 = hstart + y0i;
        int   ry1 = min(ry0 + 1, hstart + c - 1);
        float* orow = ob + (size_t)row * WW * 3;

        for (int k = 0; k < 4; ++k) {
            int ox = (t << 2) + k;
            float xsf = fminf(fmaxf((ox + 0.5f) * sx - 0.5f, 0.0f), cf - 1.0f);
            int   x0i = (int)floorf(xsf);
            float wx  = xsf - (float)x0i;
            int   rx0 = wstart + x0i;
            int   rx1 = min(rx0 + 1, wstart + c - 1);

            float p00[3], p01[3], p10[3], p11[3];
            auto fetch = [&](int y, int x, float* p) {
                int idx = y * WW + x;
                float mv = msk[idx];
                if (mv >= 0.5f) {
                    const float* q = im + (size_t)idx * 3;
                    p[0] = q[0]; p[1] = q[1]; p[2] = q[2];
                } else {
                    p[0] = 0.0f; p[1] = 0.0f; p[2] = 0.0f;
                }
            };
            fetch(ry0, rx0, p00);
            fetch(ry0, rx1, p01);
            fetch(ry1, rx0, p10);
            fetch(ry1, rx1, p11);

            float* o = orow + (size_t)ox * 3;
#pragma unroll
            for (int ch = 0; ch < 3; ++ch) {
                float top = (1.0f - wx) * p00[ch] + wx * p01[ch];
                float bot = (1.0f - wx) * p10[ch] + wx * p11[ch];
                o[ch] = (1.0f - wy) * top + wy * bot;
            }
        }
    }
}

extern "C" void kernel_launch(void* const* d_in, const int* in_sizes, int n_in,
                              void* d_out, int out_size, void* d_ws, size_t ws_size,
                              hipStream_t stream) {
    const float* masks  = (const float*)d_in[0];
    const float* images = (const float*)d_in[1];
    float* out = (float*)d_out;

    int* rowMinC = (int*)d_ws;                 // NS*HH ints
    int* rowMaxC = rowMinC + NS * HH;          // NS*HH ints

    fused_kernel<<<dim3(HH / RB, NS), 256, 0, stream>>>(masks, images, rowMinC, rowMaxC, out);
    tail_kernel <<<NS,                256, 0, stream>>>(masks, images, rowMinC, rowMaxC, out);
}

// Round 8
// 80.747 us; speedup vs baseline: 1.2423x; 1.0519x over previous
//
#include <hip/hip_runtime.h>

#define HH 1024
#define WW 1024
#define NS 16
#define RB 2                    // rows per fused block (occupancy lever)

typedef float f32x4 __attribute__((ext_vector_type(4)));

// ---------------------------------------------------------------------------
// Pass 1 (fused): one block per (RB rows, sample).
//  - preload RB mask f32x4 + 3*RB img f32x4 per thread (all loads in flight)
//  - threshold+bit-pack mask rows (shfl merges) -> LDS bits + row stats
//  - speculatively write the IDENTITY-crop result: out = bit ? img : 0
// Non-identity crops are rewritten by the tail kernel.
// RB=2 keeps live VGPRs ~55 -> ~8 waves/SIMD for deeper latency hiding.
// ---------------------------------------------------------------------------
__global__ __launch_bounds__(256)
void fused_kernel(const float* __restrict__ mask,
                  const float* __restrict__ img,
                  int* __restrict__ rowMinC,
                  int* __restrict__ rowMaxC,
                  float* __restrict__ out) {
    const int s  = blockIdx.y;
    const int r0 = blockIdx.x * RB;
    const int t  = threadIdx.x;

    const f32x4* m4 = (const f32x4*)(mask + (size_t)s * HH * WW);
    const f32x4* ip = (const f32x4*)(img + ((size_t)s * HH + r0) * WW * 3);
    f32x4*       op = (f32x4*)(out + ((size_t)s * HH + r0) * WW * 3);

    // ---- issue ALL loads first (maximum memory-level parallelism) ----
    f32x4 mv[RB];
#pragma unroll
    for (int rr = 0; rr < RB; ++rr)
        mv[rr] = __builtin_nontemporal_load(&m4[(size_t)(r0 + rr) * 256 + t]);

    f32x4 iv[RB][3];
#pragma unroll
    for (int rr = 0; rr < RB; ++rr)
#pragma unroll
        for (int j = 0; j < 3; ++j)
            iv[rr][j] = __builtin_nontemporal_load(&ip[(size_t)rr * 768 + t + (j << 8)]);

    // ---- mask phase: pack bits, per-row min/max col (runs under load latency) ----
    __shared__ unsigned int pw[RB][32];
    __shared__ int smin[RB][4], smax[RB][4];

#pragma unroll
    for (int rr = 0; rr < RB; ++rr) {
        unsigned int w = (mv[rr].x >= 0.5f ? 1u : 0u)
                       | (mv[rr].y >= 0.5f ? 2u : 0u)
                       | (mv[rr].z >= 0.5f ? 4u : 0u)
                       | (mv[rr].w >= 0.5f ? 8u : 0u);
        w |= __shfl_down(w, 1) << 4;
        w |= __shfl_down(w, 2) << 8;
        w |= __shfl_down(w, 4) << 16;

        int cmin = WW, cmax = -1;
        if ((t & 7) == 0) {
            int g = t >> 3;                            // word index 0..31
            pw[rr][g] = w;
            if (w) {
                cmin = (g << 5) + __builtin_ctz(w);
                cmax = (g << 5) + 31 - __builtin_clz(w);
            }
        }
        for (int off = 32; off > 0; off >>= 1) {
            cmin = min(cmin, __shfl_down(cmin, off));
            cmax = max(cmax, __shfl_down(cmax, off));
        }
        if ((t & 63) == 0) { smin[rr][t >> 6] = cmin; smax[rr][t >> 6] = cmax; }
    }
    __syncthreads();
    if (t < RB) {
        int cmin = min(min(smin[t][0], smin[t][1]), min(smin[t][2], smin[t][3]));
        int cmax = max(max(smax[t][0], smax[t][1]), max(smax[t][2], smax[t][3]));
        rowMinC[s * HH + r0 + t] = cmin;
        rowMaxC[s * HH + r0 + t] = cmax;
    }

    // ---- select + store (img already in registers) ----
#pragma unroll
    for (int rr = 0; rr < RB; ++rr) {
        const unsigned int* pwr = pw[rr];
#pragma unroll
        for (int j = 0; j < 3; ++j) {
            int fi = t + (j << 8);          // f32x4 index in row, 0..767
            int F  = fi << 2;               // float offset in row
            int p0 = F / 3;                 // first pixel covered
            int r  = F - p0 * 3;            // 0..2
            unsigned int b0 = (pwr[p0 >> 5] >> (p0 & 31)) & 1u;
            int p1 = p0 + 1;
            unsigned int b1 = (pwr[p1 >> 5] >> (p1 & 31)) & 1u;
            f32x4 v = iv[rr][j];
            f32x4 o;
            o.x = b0 ? v.x : 0.0f;
            o.y = ((r < 2) ? b0 : b1) ? v.y : 0.0f;
            o.z = ((r == 0) ? b0 : b1) ? v.z : 0.0f;
            o.w = b1 ? v.w : 0.0f;
            __builtin_nontemporal_store(o, &op[(size_t)rr * 768 + fi]);
        }
    }
}

// ---------------------------------------------------------------------------
// Pass 2 (tail): one block per sample. Reduce row stats -> crop params.
// Identity crop (the speculated case) -> return. Otherwise rewrite the whole
// sample with the general bilinear path (correctness fallback).
// ---------------------------------------------------------------------------
__global__ __launch_bounds__(256)
void tail_kernel(const float* __restrict__ mask,
                 const float* __restrict__ img,
                 const int* __restrict__ rowMinC,
                 const int* __restrict__ rowMaxC,
                 float* __restrict__ out) {
    const int s = blockIdx.x;
    const int t = threadIdx.x;

    int minR = HH, maxR = -1, minC = WW, maxC = -1;
#pragma unroll
    for (int m = 0; m < HH / 256; ++m) {
        int r = t + (m << 8);
        int mc = rowMaxC[s * HH + r];
        if (mc >= 0) {
            minR = min(minR, r);
            maxR = max(maxR, r);
            minC = min(minC, rowMinC[s * HH + r]);
            maxC = max(maxC, mc);
        }
    }
    for (int off = 32; off > 0; off >>= 1) {
        minR = min(minR, __shfl_down(minR, off));
        maxR = max(maxR, __shfl_down(maxR, off));
        minC = min(minC, __shfl_down(minC, off));
        maxC = max(maxC, __shfl_down(maxC, off));
    }
    __shared__ int sm[4][4];
    __shared__ int bc[3];
    int wave = t >> 6, lane = t & 63;
    if (lane == 0) { sm[wave][0] = minR; sm[wave][1] = maxR; sm[wave][2] = minC; sm[wave][3] = maxC; }
    __syncthreads();
    if (t == 0) {
        for (int wv = 1; wv < 4; ++wv) {
            minR = min(minR, sm[wv][0]);
            maxR = max(maxR, sm[wv][1]);
            minC = min(minC, sm[wv][2]);
            maxC = max(maxC, sm[wv][3]);
        }
        int xl, xr, yl, yr;
        if (maxR < 0) { xl = 0; xr = HH; } else { xl = max(minR - 1, 0); xr = maxR + 1; }
        if (maxC < 0) { yl = 0; yr = WW; } else { yl = max(minC - 1, 0); yr = maxC + 1; }
        int h = xr - xl, w = yr - yl;
        int c = min(h, w);
        bc[0] = c;
        bc[1] = xl + (h - c) / 2;
        bc[2] = yl + (w - c) / 2;
    }
    __syncthreads();
    const int c = bc[0], hstart = bc[1], wstart = bc[2];
    if (c == HH && hstart == 0 && wstart == 0) return;   // speculation was exact

    // General bilinear rewrite of the whole sample (rare fallback path).
    const float* msk = mask + (size_t)s * HH * WW;
    const float* im  = img  + (size_t)s * HH * WW * 3;
    float*       ob  = out  + (size_t)s * HH * WW * 3;

    float cf = (float)c;
    float sy = cf / (float)HH;
    float sx = cf / (float)WW;

    for (int row = 0; row < HH; ++row) {
        float ysf = fminf(fmaxf((row + 0.5f) * sy - 0.5f, 0.0f), cf - 1.0f);
        int   y0i = (int)floorf(ysf);
        float wy  = ysf - (float)y0i;
        int   ry0 = hstart + y0i;
        int   ry1 = min(ry0 + 1, hstart + c - 1);
        float* orow = ob + (size_t)row * WW * 3;

        for (int k = 0; k < 4; ++k) {
            int ox = (t << 2) + k;
            float xsf = fminf(fmaxf((ox + 0.5f) * sx - 0.5f, 0.0f), cf - 1.0f);
            int   x0i = (int)floorf(xsf);
            float wx  = xsf - (float)x0i;
            int   rx0 = wstart + x0i;
            int   rx1 = min(rx0 + 1, wstart + c - 1);

            float p00[3], p01[3], p10[3], p11[3];
            auto fetch = [&](int y, int x, float* p) {
                int idx = y * WW + x;
                float mv = msk[idx];
                if (mv >= 0.5f) {
                    const float* q = im + (size_t)idx * 3;
                    p[0] = q[0]; p[1] = q[1]; p[2] = q[2];
                } else {
                    p[0] = 0.0f; p[1] = 0.0f; p[2] = 0.0f;
                }
            };
            fetch(ry0, rx0, p00);
            fetch(ry0, rx1, p01);
            fetch(ry1, rx0, p10);
            fetch(ry1, rx1, p11);

            float* o = orow + (size_t)ox * 3;
#pragma unroll
            for (int ch = 0; ch < 3; ++ch) {
                float top = (1.0f - wx) * p00[ch] + wx * p01[ch];
                float bot = (1.0f - wx) * p10[ch] + wx * p11[ch];
                o[ch] = (1.0f - wy) * top + wy * bot;
            }
        }
    }
}

extern "C" void kernel_launch(void* const* d_in, const int* in_sizes, int n_in,
                              void* d_out, int out_size, void* d_ws, size_t ws_size,
                              hipStream_t stream) {
    const float* masks  = (const float*)d_in[0];
    const float* images = (const float*)d_in[1];
    float* out = (float*)d_out;

    int* rowMinC = (int*)d_ws;                 // NS*HH ints
    int* rowMaxC = rowMinC + NS * HH;          // NS*HH ints

    fused_kernel<<<dim3(HH / RB, NS), 256, 0, stream>>>(masks, images, rowMinC, rowMaxC, out);
    tail_kernel <<<NS,                256, 0, stream>>>(masks, images, rowMinC, rowMaxC, out);
}